// Round 1
// baseline (6979.900 us; speedup 1.0000x reference)
//
#include <hip/hip_runtime.h>

#define NA 100000
#define NB 100000
#define ND 50000
#define HDIM 128
#define DOUT 16

// ---- workspace layout (float element offsets) ----
static const size_t OFF_W00  = 0;                       // [128*128]
static const size_t OFF_W01  = OFF_W00 + HDIM*HDIM;
static const size_t OFF_W12  = OFF_W01 + HDIM*HDIM;
static const size_t OFF_W13  = OFF_W12 + HDIM*HDIM;
static const size_t OFF_W20  = OFF_W13 + HDIM*HDIM;     // [128*16]
static const size_t OFF_W21  = OFF_W20 + HDIM*DOUT;
static const size_t OFF_DEG0 = OFF_W21 + HDIM*DOUT;     // [ND]
static const size_t OFF_DEG1 = OFF_DEG0 + ND;           // [ND]
static const size_t OFF_DEG2 = OFF_DEG1 + ND;           // [NA]
static const size_t OFF_DEG3 = OFF_DEG2 + NA;           // [NB]
static const size_t OFF_R1   = (OFF_DEG3 + NB + 255) & ~((size_t)255); // h1a [NA*128]
static const size_t OFF_R2   = OFF_R1 + (size_t)NA*HDIM;               // h0d [ND*128]
static const size_t OFF_R3   = OFF_R2 + (size_t)ND*HDIM;               // agg scratch [NA*128]
static const size_t OFF_R4   = OFF_R3 + (size_t)NA*HDIM;               // h1b [NB*128]

// ---- W_r = coef[r,0]*basis[0] + coef[r,1]*basis[1] ----
__global__ __launch_bounds__(256) void k_weights(const float* __restrict__ basis,
                                                 const float* __restrict__ coef,
                                                 float* __restrict__ W0, float* __restrict__ W1,
                                                 int r0, int r1, int n) {
    int i = blockIdx.x * 256 + threadIdx.x;
    if (i >= n) return;
    float b0 = basis[i], b1 = basis[n + i];
    W0[i] = coef[r0*2+0]*b0 + coef[r0*2+1]*b1;
    W1[i] = coef[r1*2+0]*b0 + coef[r1*2+1]*b1;
}

__global__ __launch_bounds__(256) void k_degree(const int* __restrict__ dst, int E,
                                                float* __restrict__ deg) {
    int i = blockIdx.x * 256 + threadIdx.x;
    if (i < E) atomicAdd(&deg[dst[i]], 1.0f);
}

// scatter-add: 32 threads per edge, 4 channels each (float4 gather + 4 f32 atomics)
__global__ __launch_bounds__(256) void k_scatter(const float* __restrict__ feat,
                                                 const int* __restrict__ src,
                                                 const int* __restrict__ dst,
                                                 int E, float* __restrict__ agg) {
    int t = blockIdx.x * 256 + threadIdx.x;
    int e = t >> 5;
    if (e >= E) return;
    int c = (t & 31) * 4;
    int s = src[e], d = dst[e];
    const float4 v = *reinterpret_cast<const float4*>(feat + (size_t)s*HDIM + c);
    float* p = agg + (size_t)d*HDIM + c;
    atomicAdd(p+0, v.x); atomicAdd(p+1, v.y); atomicAdd(p+2, v.z); atomicAdd(p+3, v.w);
}

// out[row] = relu( (A[row]/degA) @ WA + (B[row]/degB) @ WB + bias )   dout=128
__global__ __launch_bounds__(256) void k_gemm2_128(const float* __restrict__ A, const float* __restrict__ B,
                                                   const float* __restrict__ WA, const float* __restrict__ WB,
                                                   const float* __restrict__ degA, const float* __restrict__ degB,
                                                   const float* __restrict__ bias,
                                                   float* __restrict__ out, int nrows, int relu) {
    int t = threadIdx.x;
    int row = blockIdx.x * 8 + (t >> 5);
    if (row >= nrows) return;
    int c = (t & 31) * 4;
    float sa = 1.0f / fmaxf(degA[row], 1.0f);
    float sb = 1.0f / fmaxf(degB[row], 1.0f);
    const float* a = A + (size_t)row*HDIM;
    const float* b = B + (size_t)row*HDIM;
    float4 acc = make_float4(0.f, 0.f, 0.f, 0.f);
    #pragma unroll 8
    for (int i = 0; i < HDIM; ++i) {
        float av = a[i]*sa, bv = b[i]*sb;
        float4 wa = *reinterpret_cast<const float4*>(WA + (size_t)i*HDIM + c);
        float4 wb = *reinterpret_cast<const float4*>(WB + (size_t)i*HDIM + c);
        acc.x += av*wa.x + bv*wb.x;
        acc.y += av*wa.y + bv*wb.y;
        acc.z += av*wa.z + bv*wb.z;
        acc.w += av*wa.w + bv*wb.w;
    }
    float4 bi = *reinterpret_cast<const float4*>(bias + c);
    acc.x += bi.x; acc.y += bi.y; acc.z += bi.z; acc.w += bi.w;
    if (relu) {
        acc.x = fmaxf(acc.x, 0.f); acc.y = fmaxf(acc.y, 0.f);
        acc.z = fmaxf(acc.z, 0.f); acc.w = fmaxf(acc.w, 0.f);
    }
    *reinterpret_cast<float4*>(out + (size_t)row*HDIM + c) = acc;
}

// single-input variant, dout=128
__global__ __launch_bounds__(256) void k_gemm1_128(const float* __restrict__ A,
                                                   const float* __restrict__ WA,
                                                   const float* __restrict__ degA,
                                                   const float* __restrict__ bias,
                                                   float* __restrict__ out, int nrows, int relu) {
    int t = threadIdx.x;
    int row = blockIdx.x * 8 + (t >> 5);
    if (row >= nrows) return;
    int c = (t & 31) * 4;
    float sa = 1.0f / fmaxf(degA[row], 1.0f);
    const float* a = A + (size_t)row*HDIM;
    float4 acc = make_float4(0.f, 0.f, 0.f, 0.f);
    #pragma unroll 8
    for (int i = 0; i < HDIM; ++i) {
        float av = a[i]*sa;
        float4 wa = *reinterpret_cast<const float4*>(WA + (size_t)i*HDIM + c);
        acc.x += av*wa.x; acc.y += av*wa.y; acc.z += av*wa.z; acc.w += av*wa.w;
    }
    float4 bi = *reinterpret_cast<const float4*>(bias + c);
    acc.x += bi.x; acc.y += bi.y; acc.z += bi.z; acc.w += bi.w;
    if (relu) {
        acc.x = fmaxf(acc.x, 0.f); acc.y = fmaxf(acc.y, 0.f);
        acc.z = fmaxf(acc.z, 0.f); acc.w = fmaxf(acc.w, 0.f);
    }
    *reinterpret_cast<float4*>(out + (size_t)row*HDIM + c) = acc;
}

// final layer: dout=16, two inputs, no relu; 64 rows/block, 4 threads/row, 4 cols/thread
__global__ __launch_bounds__(256) void k_gemm2_16(const float* __restrict__ A, const float* __restrict__ B,
                                                  const float* __restrict__ WA, const float* __restrict__ WB,
                                                  const float* __restrict__ degA, const float* __restrict__ degB,
                                                  const float* __restrict__ bias,
                                                  float* __restrict__ out, int nrows) {
    int t = threadIdx.x;
    int row = blockIdx.x * 64 + (t >> 2);
    if (row >= nrows) return;
    int c = (t & 3) * 4;
    float sa = 1.0f / fmaxf(degA[row], 1.0f);
    float sb = 1.0f / fmaxf(degB[row], 1.0f);
    const float* a = A + (size_t)row*HDIM;
    const float* b = B + (size_t)row*HDIM;
    float4 acc = make_float4(0.f, 0.f, 0.f, 0.f);
    #pragma unroll 8
    for (int i = 0; i < HDIM; ++i) {
        float av = a[i]*sa, bv = b[i]*sb;
        float4 wa = *reinterpret_cast<const float4*>(WA + (size_t)i*DOUT + c);
        float4 wb = *reinterpret_cast<const float4*>(WB + (size_t)i*DOUT + c);
        acc.x += av*wa.x + bv*wb.x;
        acc.y += av*wa.y + bv*wb.y;
        acc.z += av*wa.z + bv*wb.z;
        acc.w += av*wa.w + bv*wb.w;
    }
    float4 bi = *reinterpret_cast<const float4*>(bias + c);
    acc.x += bi.x; acc.y += bi.y; acc.z += bi.z; acc.w += bi.w;
    *reinterpret_cast<float4*>(out + (size_t)row*DOUT + c) = acc;
}

extern "C" void kernel_launch(void* const* d_in, const int* in_sizes, int n_in,
                              void* d_out, int out_size, void* d_ws, size_t ws_size,
                              hipStream_t stream) {
    const float* feat_a = (const float*)d_in[0];
    const float* feat_b = (const float*)d_in[1];
    // feat_d (d_in[2]) is never needed: h0['a'], h0['b'], h1['d'] are dead.
    const float* basis0 = (const float*)d_in[3];
    const float* coef0  = (const float*)d_in[4];
    const float* bias0  = (const float*)d_in[5];
    const float* basis1 = (const float*)d_in[6];
    const float* coef1  = (const float*)d_in[7];
    const float* bias1  = (const float*)d_in[8];
    const float* basis2 = (const float*)d_in[9];
    const float* coef2  = (const float*)d_in[10];
    const float* bias2  = (const float*)d_in[11];
    const int* e0_src = (const int*)d_in[12]; const int* e0_dst = (const int*)d_in[13];
    const int* e1_src = (const int*)d_in[14]; const int* e1_dst = (const int*)d_in[15];
    const int* e2_src = (const int*)d_in[16]; const int* e2_dst = (const int*)d_in[17];
    const int* e3_src = (const int*)d_in[18]; const int* e3_dst = (const int*)d_in[19];
    const int E0 = in_sizes[12], E1 = in_sizes[14], E2 = in_sizes[16], E3 = in_sizes[18];

    float* ws = (float*)d_ws;
    float* W00 = ws + OFF_W00; float* W01 = ws + OFF_W01;
    float* W12 = ws + OFF_W12; float* W13 = ws + OFF_W13;
    float* W20 = ws + OFF_W20; float* W21 = ws + OFF_W21;
    float* deg0 = ws + OFF_DEG0; float* deg1 = ws + OFF_DEG1;
    float* deg2 = ws + OFF_DEG2; float* deg3 = ws + OFF_DEG3;
    float* h1a = ws + OFF_R1;   // [NA,128]
    float* h0d = ws + OFF_R2;   // [ND,128]
    float* agg = ws + OFF_R3;   // scratch [NA,128]
    float* h1b = ws + OFF_R4;   // [NB,128]
    float* out = (float*)d_out;

    const size_t AGG_BYTES_FULL = (size_t)NA*HDIM*sizeof(float);   // 51.2 MB
    const size_t DEG_BYTES = (OFF_R1 - OFF_DEG0) * sizeof(float);

    // 1. weights
    k_weights<<<(HDIM*HDIM+255)/256, 256, 0, stream>>>(basis0, coef0, W00, W01, 0, 1, HDIM*HDIM);
    k_weights<<<(HDIM*HDIM+255)/256, 256, 0, stream>>>(basis1, coef1, W12, W13, 2, 3, HDIM*HDIM);
    k_weights<<<(HDIM*DOUT+255)/256, 256, 0, stream>>>(basis2, coef2, W20, W21, 0, 1, HDIM*DOUT);

    // 2. degrees (same per relation across layers)
    hipMemsetAsync(deg0, 0, DEG_BYTES, stream);
    k_degree<<<(E0+255)/256, 256, 0, stream>>>(e0_dst, E0, deg0);
    k_degree<<<(E1+255)/256, 256, 0, stream>>>(e1_dst, E1, deg1);
    k_degree<<<(E2+255)/256, 256, 0, stream>>>(e2_dst, E2, deg2);
    k_degree<<<(E3+255)/256, 256, 0, stream>>>(e3_dst, E3, deg3);

    // 3. layer 0 (only h0['d'] needed): agg(feat_a via e0), agg(feat_b via e1)
    hipMemsetAsync(agg, 0, AGG_BYTES_FULL, stream);
    float* aggA = agg; float* aggB = agg + (size_t)ND*HDIM;
    k_scatter<<<((size_t)E0*32+255)/256, 256, 0, stream>>>(feat_a, e0_src, e0_dst, E0, aggA);
    k_scatter<<<((size_t)E1*32+255)/256, 256, 0, stream>>>(feat_b, e1_src, e1_dst, E1, aggB);
    k_gemm2_128<<<(ND+7)/8, 256, 0, stream>>>(aggA, aggB, W00, W01, deg0, deg1, bias0, h0d, ND, 1);

    // 4. layer 1: h1a = relu(agg(h0d via e2) @ W12), h1b = relu(agg(h0d via e3) @ W13)
    hipMemsetAsync(agg, 0, AGG_BYTES_FULL, stream);
    k_scatter<<<((size_t)E2*32+255)/256, 256, 0, stream>>>(h0d, e2_src, e2_dst, E2, agg);
    k_gemm1_128<<<(NA+7)/8, 256, 0, stream>>>(agg, W12, deg2, bias1, h1a, NA, 1);

    hipMemsetAsync(agg, 0, AGG_BYTES_FULL, stream);
    k_scatter<<<((size_t)E3*32+255)/256, 256, 0, stream>>>(h0d, e3_src, e3_dst, E3, agg);
    k_gemm1_128<<<(NB+7)/8, 256, 0, stream>>>(agg, W13, deg3, bias1, h1b, NB, 1);

    // 5. layer 2 (output only for 'd'): agg(h1a via e0), agg(h1b via e1)
    hipMemsetAsync(agg, 0, AGG_BYTES_FULL, stream);
    k_scatter<<<((size_t)E0*32+255)/256, 256, 0, stream>>>(h1a, e0_src, e0_dst, E0, aggA);
    k_scatter<<<((size_t)E1*32+255)/256, 256, 0, stream>>>(h1b, e1_src, e1_dst, E1, aggB);
    k_gemm2_16<<<(ND+63)/64, 256, 0, stream>>>(aggA, aggB, W20, W21, deg0, deg1, bias2, out, ND);
}

// Round 2
// 1283.979 us; speedup vs baseline: 5.4361x; 5.4361x over previous
//
#include <hip/hip_runtime.h>

#define NA 100000
#define NB 100000
#define ND 50000
#define HDIM 128
#define DOUT 16

// ---------------- weights: W_r = coef[r,0]*basis[0] + coef[r,1]*basis[1] ----------------
__global__ __launch_bounds__(256) void k_weights(const float* __restrict__ basis,
                                                 const float* __restrict__ coef,
                                                 float* __restrict__ W0, float* __restrict__ W1,
                                                 int r0, int r1, int n) {
    int i = blockIdx.x * 256 + threadIdx.x;
    if (i >= n) return;
    float b0 = basis[i], b1 = basis[n + i];
    W0[i] = coef[r0*2+0]*b0 + coef[r0*2+1]*b1;
    W1[i] = coef[r1*2+0]*b0 + coef[r1*2+1]*b1;
}

// ---------------- CSR build ----------------
__global__ __launch_bounds__(256) void k_degree_i(const int* __restrict__ dst, int E,
                                                  int* __restrict__ deg) {
    int i = blockIdx.x * 256 + threadIdx.x;
    if (i < E) atomicAdd(&deg[dst[i]], 1);
}

// block-level inclusive scan; offs[i+1] = partial inclusive, bsum[blk] = block total
__global__ __launch_bounds__(256) void k_scan1(const int* __restrict__ deg,
                                               int* __restrict__ offs,
                                               int* __restrict__ bsum, int N) {
    __shared__ int sh[256];
    int i = blockIdx.x * 256 + threadIdx.x;
    int v = (i < N) ? deg[i] : 0;
    sh[threadIdx.x] = v;
    __syncthreads();
    for (int off = 1; off < 256; off <<= 1) {
        int t = (threadIdx.x >= off) ? sh[threadIdx.x - off] : 0;
        __syncthreads();
        sh[threadIdx.x] += t;
        __syncthreads();
    }
    if (i < N) offs[i + 1] = sh[threadIdx.x];
    if (threadIdx.x == 255) bsum[blockIdx.x] = sh[255];
    if (i == 0) offs[0] = 0;
}

// single-block scan of block totals (nb <= 1024)
__global__ __launch_bounds__(1024) void k_scan2(int* __restrict__ bsum, int nb) {
    __shared__ int sh[1024];
    int t = threadIdx.x;
    sh[t] = (t < nb) ? bsum[t] : 0;
    __syncthreads();
    for (int off = 1; off < 1024; off <<= 1) {
        int v = (t >= off) ? sh[t - off] : 0;
        __syncthreads();
        sh[t] += v;
        __syncthreads();
    }
    if (t < nb) bsum[t] = sh[t];
}

__global__ __launch_bounds__(256) void k_scan3(int* __restrict__ offs,
                                               const int* __restrict__ bsum, int N) {
    int i = blockIdx.x * 256 + threadIdx.x;
    if (blockIdx.x > 0 && i < N) offs[i + 1] += bsum[blockIdx.x - 1];
}

__global__ __launch_bounds__(256) void k_copy_i(const int* __restrict__ a,
                                                int* __restrict__ b, int N) {
    int i = blockIdx.x * 256 + threadIdx.x;
    if (i < N) b[i] = a[i];
}

__global__ __launch_bounds__(256) void k_fill(const int* __restrict__ src,
                                              const int* __restrict__ dst, int E,
                                              int* __restrict__ cursor,
                                              int* __restrict__ csr) {
    int e = blockIdx.x * 256 + threadIdx.x;
    if (e >= E) return;
    int p = atomicAdd(&cursor[dst[e]], 1);
    csr[p] = src[e];
}

// ---------------- gather (CSR, normalized): one wave per dst row ----------------
__global__ __launch_bounds__(256) void k_gather128(const float* __restrict__ feat,
                                                   const int* __restrict__ offs,
                                                   const int* __restrict__ csr,
                                                   float* __restrict__ out, int nrows) {
    int w = threadIdx.x >> 6;
    int lane = threadIdx.x & 63;
    int row = blockIdx.x * 4 + w;
    if (row >= nrows) return;
    int s0 = offs[row], s1 = offs[row + 1];
    float2 acc = make_float2(0.f, 0.f);
    int j = s0;
    for (; j + 1 < s1; j += 2) {
        int sA = csr[j], sB = csr[j + 1];
        const float2 a = *reinterpret_cast<const float2*>(feat + (size_t)sA*HDIM + lane*2);
        const float2 b = *reinterpret_cast<const float2*>(feat + (size_t)sB*HDIM + lane*2);
        acc.x += a.x + b.x; acc.y += a.y + b.y;
    }
    if (j < s1) {
        int sA = csr[j];
        const float2 a = *reinterpret_cast<const float2*>(feat + (size_t)sA*HDIM + lane*2);
        acc.x += a.x; acc.y += a.y;
    }
    float sc = 1.0f / fmaxf((float)(s1 - s0), 1.0f);
    *reinterpret_cast<float2*>(out + (size_t)row*HDIM + lane*2) = make_float2(acc.x*sc, acc.y*sc);
}

// ---------------- GEMMs (inputs already normalized) ----------------
__global__ __launch_bounds__(256) void k_gemm2_128(const float* __restrict__ A, const float* __restrict__ B,
                                                   const float* __restrict__ WA, const float* __restrict__ WB,
                                                   const float* __restrict__ bias,
                                                   float* __restrict__ out, int nrows) {
    int t = threadIdx.x;
    int row = blockIdx.x * 8 + (t >> 5);
    if (row >= nrows) return;
    int c = (t & 31) * 4;
    const float* a = A + (size_t)row*HDIM;
    const float* b = B + (size_t)row*HDIM;
    float4 acc = make_float4(0.f, 0.f, 0.f, 0.f);
    #pragma unroll 8
    for (int i = 0; i < HDIM; ++i) {
        float av = a[i], bv = b[i];
        float4 wa = *reinterpret_cast<const float4*>(WA + (size_t)i*HDIM + c);
        float4 wb = *reinterpret_cast<const float4*>(WB + (size_t)i*HDIM + c);
        acc.x += av*wa.x + bv*wb.x;
        acc.y += av*wa.y + bv*wb.y;
        acc.z += av*wa.z + bv*wb.z;
        acc.w += av*wa.w + bv*wb.w;
    }
    float4 bi = *reinterpret_cast<const float4*>(bias + c);
    acc.x = fmaxf(acc.x + bi.x, 0.f); acc.y = fmaxf(acc.y + bi.y, 0.f);
    acc.z = fmaxf(acc.z + bi.z, 0.f); acc.w = fmaxf(acc.w + bi.w, 0.f);
    *reinterpret_cast<float4*>(out + (size_t)row*HDIM + c) = acc;
}

__global__ __launch_bounds__(256) void k_gemm1_128(const float* __restrict__ A,
                                                   const float* __restrict__ WA,
                                                   const float* __restrict__ bias,
                                                   float* __restrict__ out, int nrows) {
    int t = threadIdx.x;
    int row = blockIdx.x * 8 + (t >> 5);
    if (row >= nrows) return;
    int c = (t & 31) * 4;
    const float* a = A + (size_t)row*HDIM;
    float4 acc = make_float4(0.f, 0.f, 0.f, 0.f);
    #pragma unroll 8
    for (int i = 0; i < HDIM; ++i) {
        float av = a[i];
        float4 wa = *reinterpret_cast<const float4*>(WA + (size_t)i*HDIM + c);
        acc.x += av*wa.x; acc.y += av*wa.y; acc.z += av*wa.z; acc.w += av*wa.w;
    }
    float4 bi = *reinterpret_cast<const float4*>(bias + c);
    acc.x = fmaxf(acc.x + bi.x, 0.f); acc.y = fmaxf(acc.y + bi.y, 0.f);
    acc.z = fmaxf(acc.z + bi.z, 0.f); acc.w = fmaxf(acc.w + bi.w, 0.f);
    *reinterpret_cast<float4*>(out + (size_t)row*HDIM + c) = acc;
}

// transform h1 (post-relu) by W2 -> 16-wide table; 4 lanes/row
__global__ __launch_bounds__(256) void k_trans16(const float* __restrict__ A,
                                                 const float* __restrict__ W,
                                                 float* __restrict__ out, int nrows) {
    int t = threadIdx.x;
    int row = blockIdx.x * 64 + (t >> 2);
    if (row >= nrows) return;
    int c = (t & 3) * 4;
    const float* a = A + (size_t)row*HDIM;
    float4 acc = make_float4(0.f, 0.f, 0.f, 0.f);
    #pragma unroll 8
    for (int i = 0; i < HDIM; ++i) {
        float av = a[i];
        float4 w = *reinterpret_cast<const float4*>(W + (size_t)i*DOUT + c);
        acc.x += av*w.x; acc.y += av*w.y; acc.z += av*w.z; acc.w += av*w.w;
    }
    *reinterpret_cast<float4*>(out + (size_t)row*DOUT + c) = acc;
}

// final: out[d] = gather(t0 via csr0)/deg0 + gather(t1 via csr1)/deg1 + bias
__global__ __launch_bounds__(256) void k_gather16_combine(const float* __restrict__ t0,
                                                          const float* __restrict__ t1,
                                                          const int* __restrict__ offs0,
                                                          const int* __restrict__ csr0,
                                                          const int* __restrict__ offs1,
                                                          const int* __restrict__ csr1,
                                                          const float* __restrict__ bias,
                                                          float* __restrict__ out, int nrows) {
    int t = threadIdx.x;
    int row = blockIdx.x * 64 + (t >> 2);
    if (row >= nrows) return;
    int c = (t & 3) * 4;
    float4 acc = make_float4(0.f, 0.f, 0.f, 0.f);
    int s0 = offs0[row], s1 = offs0[row + 1];
    for (int j = s0; j < s1; ++j) {
        int s = csr0[j];
        float4 v = *reinterpret_cast<const float4*>(t0 + (size_t)s*DOUT + c);
        acc.x += v.x; acc.y += v.y; acc.z += v.z; acc.w += v.w;
    }
    float sc = 1.0f / fmaxf((float)(s1 - s0), 1.0f);
    acc.x *= sc; acc.y *= sc; acc.z *= sc; acc.w *= sc;
    float4 acc2 = make_float4(0.f, 0.f, 0.f, 0.f);
    int u0 = offs1[row], u1 = offs1[row + 1];
    for (int j = u0; j < u1; ++j) {
        int s = csr1[j];
        float4 v = *reinterpret_cast<const float4*>(t1 + (size_t)s*DOUT + c);
        acc2.x += v.x; acc2.y += v.y; acc2.z += v.z; acc2.w += v.w;
    }
    float sc2 = 1.0f / fmaxf((float)(u1 - u0), 1.0f);
    float4 bi = *reinterpret_cast<const float4*>(bias + c);
    acc.x += acc2.x*sc2 + bi.x; acc.y += acc2.y*sc2 + bi.y;
    acc.z += acc2.z*sc2 + bi.z; acc.w += acc2.w*sc2 + bi.w;
    *reinterpret_cast<float4*>(out + (size_t)row*DOUT + c) = acc;
}

extern "C" void kernel_launch(void* const* d_in, const int* in_sizes, int n_in,
                              void* d_out, int out_size, void* d_ws, size_t ws_size,
                              hipStream_t stream) {
    const float* feat_a = (const float*)d_in[0];
    const float* feat_b = (const float*)d_in[1];
    const float* basis0 = (const float*)d_in[3];
    const float* coef0  = (const float*)d_in[4];
    const float* bias0  = (const float*)d_in[5];
    const float* basis1 = (const float*)d_in[6];
    const float* coef1  = (const float*)d_in[7];
    const float* bias1  = (const float*)d_in[8];
    const float* basis2 = (const float*)d_in[9];
    const float* coef2  = (const float*)d_in[10];
    const float* bias2  = (const float*)d_in[11];
    const int* e_src[4] = {(const int*)d_in[12], (const int*)d_in[14], (const int*)d_in[16], (const int*)d_in[18]};
    const int* e_dst[4] = {(const int*)d_in[13], (const int*)d_in[15], (const int*)d_in[17], (const int*)d_in[19]};
    const int  E[4]     = {in_sizes[12], in_sizes[14], in_sizes[16], in_sizes[18]};
    const int  Nd[4]    = {ND, ND, NA, NB};   // dst-node counts per relation

    // ---- workspace carve-up (256B-aligned chunks) ----
    char* base = (char*)d_ws;
    auto alloc = [&](size_t bytes) { char* p = base; base += (bytes + 255) & ~(size_t)255; return p; };
    float* W00 = (float*)alloc(HDIM*HDIM*4);
    float* W01 = (float*)alloc(HDIM*HDIM*4);
    float* W12 = (float*)alloc(HDIM*HDIM*4);
    float* W13 = (float*)alloc(HDIM*HDIM*4);
    float* W20 = (float*)alloc(HDIM*DOUT*4);
    float* W21 = (float*)alloc(HDIM*DOUT*4);
    int* offs[4]; int* csr[4];
    for (int r = 0; r < 4; ++r) offs[r] = (int*)alloc((Nd[r] + 1) * 4);
    for (int r = 0; r < 4; ++r) csr[r]  = (int*)alloc((size_t)E[r] * 4);
    int* bsum   = (int*)alloc(1024 * 4);
    int* ideg   = (int*)alloc(NA * 4);       // reused per relation
    int* cursor = (int*)alloc(NA * 4);       // reused per relation
    float* agg  = (float*)alloc((size_t)NA*HDIM*4);   // 51.2MB scratch (also t1a/t1b home)
    float* h0d  = (float*)alloc((size_t)ND*HDIM*4);
    float* h1a  = (float*)alloc((size_t)NA*HDIM*4);
    float* h1b  = (float*)alloc((size_t)NB*HDIM*4);
    float* aggA = agg;                       // [ND,128] layer-0
    float* aggB = agg + (size_t)ND*HDIM;
    float* t1a  = agg;                       // [NA,16] layer-2 (agg dead by then)
    float* t1b  = agg + (size_t)NA*DOUT;
    float* out  = (float*)d_out;

    // ---- 1. relation weights ----
    k_weights<<<(HDIM*HDIM+255)/256, 256, 0, stream>>>(basis0, coef0, W00, W01, 0, 1, HDIM*HDIM);
    k_weights<<<(HDIM*HDIM+255)/256, 256, 0, stream>>>(basis1, coef1, W12, W13, 2, 3, HDIM*HDIM);
    k_weights<<<(HDIM*DOUT+255)/256, 256, 0, stream>>>(basis2, coef2, W20, W21, 0, 1, HDIM*DOUT);

    // ---- 2. CSR per relation ----
    for (int r = 0; r < 4; ++r) {
        int N = Nd[r], e = E[r];
        int nb = (N + 255) / 256;
        hipMemsetAsync(ideg, 0, (size_t)N * 4, stream);
        k_degree_i<<<(e+255)/256, 256, 0, stream>>>(e_dst[r], e, ideg);
        k_scan1<<<nb, 256, 0, stream>>>(ideg, offs[r], bsum, N);
        k_scan2<<<1, 1024, 0, stream>>>(bsum, nb);
        k_scan3<<<nb, 256, 0, stream>>>(offs[r], bsum, N);
        k_copy_i<<<nb, 256, 0, stream>>>(offs[r], cursor, N);
        k_fill<<<(e+255)/256, 256, 0, stream>>>(e_src[r], e_dst[r], e, cursor, csr[r]);
    }

    // ---- 3. layer 0: h0d = relu(agg_a @ W00 + agg_b @ W01 + bias0) ----
    k_gather128<<<(ND+3)/4, 256, 0, stream>>>(feat_a, offs[0], csr[0], aggA, ND);
    k_gather128<<<(ND+3)/4, 256, 0, stream>>>(feat_b, offs[1], csr[1], aggB, ND);
    k_gemm2_128<<<(ND+7)/8, 256, 0, stream>>>(aggA, aggB, W00, W01, bias0, h0d, ND);

    // ---- 4. layer 1: h1a, h1b ----
    k_gather128<<<(NA+3)/4, 256, 0, stream>>>(h0d, offs[2], csr[2], h1b, NA);   // borrow h1b as scratch
    k_gemm1_128<<<(NA+7)/8, 256, 0, stream>>>(h1b, W12, bias1, h1a, NA);
    k_gather128<<<(NB+3)/4, 256, 0, stream>>>(h0d, offs[3], csr[3], agg, NB);
    k_gemm1_128<<<(NB+7)/8, 256, 0, stream>>>(agg, W13, bias1, h1b, NB);

    // ---- 5. layer 2 (transform-then-aggregate, dout=16) ----
    k_trans16<<<(NA+63)/64, 256, 0, stream>>>(h1a, W20, t1a, NA);
    k_trans16<<<(NB+63)/64, 256, 0, stream>>>(h1b, W21, t1b, NB);
    k_gather16_combine<<<(ND+63)/64, 256, 0, stream>>>(t1a, t1b, offs[0], csr[0], offs[1], csr[1],
                                                       bias2, out, ND);
}

// Round 3
// 833.967 us; speedup vs baseline: 8.3695x; 1.5396x over previous
//
#include <hip/hip_runtime.h>

#define NA 100000
#define NB 100000
#define ND 50000
#define HDIM 128
#define DOUT 16
#define PA 132   // LDS pitch in floats for 128-wide tiles (breaks pow2 bank stride)

// ---------------- weights: W_r = coef[r,0]*basis[0] + coef[r,1]*basis[1] ----------------
__global__ __launch_bounds__(256) void k_weights(const float* __restrict__ basis,
                                                 const float* __restrict__ coef,
                                                 float* __restrict__ W0, float* __restrict__ W1,
                                                 int r0, int r1, int n) {
    int i = blockIdx.x * 256 + threadIdx.x;
    if (i >= n) return;
    float b0 = basis[i], b1 = basis[n + i];
    W0[i] = coef[r0*2+0]*b0 + coef[r0*2+1]*b1;
    W1[i] = coef[r1*2+0]*b0 + coef[r1*2+1]*b1;
}

// ---------------- CSR build ----------------
__global__ __launch_bounds__(256) void k_degree_i(const int* __restrict__ dst, int E,
                                                  int* __restrict__ deg) {
    int i = blockIdx.x * 256 + threadIdx.x;
    if (i < E) atomicAdd(&deg[dst[i]], 1);
}

__global__ __launch_bounds__(256) void k_scan1(const int* __restrict__ deg,
                                               int* __restrict__ offs,
                                               int* __restrict__ bsum, int N) {
    __shared__ int sh[256];
    int i = blockIdx.x * 256 + threadIdx.x;
    int v = (i < N) ? deg[i] : 0;
    sh[threadIdx.x] = v;
    __syncthreads();
    for (int off = 1; off < 256; off <<= 1) {
        int t = (threadIdx.x >= off) ? sh[threadIdx.x - off] : 0;
        __syncthreads();
        sh[threadIdx.x] += t;
        __syncthreads();
    }
    if (i < N) offs[i + 1] = sh[threadIdx.x];
    if (threadIdx.x == 255) bsum[blockIdx.x] = sh[255];
    if (i == 0) offs[0] = 0;
}

__global__ __launch_bounds__(1024) void k_scan2(int* __restrict__ bsum, int nb) {
    __shared__ int sh[1024];
    int t = threadIdx.x;
    sh[t] = (t < nb) ? bsum[t] : 0;
    __syncthreads();
    for (int off = 1; off < 1024; off <<= 1) {
        int v = (t >= off) ? sh[t - off] : 0;
        __syncthreads();
        sh[t] += v;
        __syncthreads();
    }
    if (t < nb) bsum[t] = sh[t];
}

__global__ __launch_bounds__(256) void k_scan3(int* __restrict__ offs,
                                               const int* __restrict__ bsum, int N) {
    int i = blockIdx.x * 256 + threadIdx.x;
    if (blockIdx.x > 0 && i < N) offs[i + 1] += bsum[blockIdx.x - 1];
}

__global__ __launch_bounds__(256) void k_copy_i(const int* __restrict__ a,
                                                int* __restrict__ b, int N) {
    int i = blockIdx.x * 256 + threadIdx.x;
    if (i < N) b[i] = a[i];
}

__global__ __launch_bounds__(256) void k_fill(const int* __restrict__ src,
                                              const int* __restrict__ dst, int E,
                                              int* __restrict__ cursor,
                                              int* __restrict__ csr) {
    int e = blockIdx.x * 256 + threadIdx.x;
    if (e >= E) return;
    int p = atomicAdd(&cursor[dst[e]], 1);
    csr[p] = src[e];
}

// ---------------- gather (CSR, normalized): one wave per dst row ----------------
__global__ __launch_bounds__(256) void k_gather128(const float* __restrict__ feat,
                                                   const int* __restrict__ offs,
                                                   const int* __restrict__ csr,
                                                   float* __restrict__ out, int nrows) {
    int w = threadIdx.x >> 6;
    int lane = threadIdx.x & 63;
    int row = blockIdx.x * 4 + w;
    if (row >= nrows) return;
    int s0 = offs[row], s1 = offs[row + 1];
    float2 acc = make_float2(0.f, 0.f);
    int j = s0;
    for (; j + 1 < s1; j += 2) {
        int sA = csr[j], sB = csr[j + 1];
        const float2 a = *reinterpret_cast<const float2*>(feat + (size_t)sA*HDIM + lane*2);
        const float2 b = *reinterpret_cast<const float2*>(feat + (size_t)sB*HDIM + lane*2);
        acc.x += a.x + b.x; acc.y += a.y + b.y;
    }
    if (j < s1) {
        int sA = csr[j];
        const float2 a = *reinterpret_cast<const float2*>(feat + (size_t)sA*HDIM + lane*2);
        acc.x += a.x; acc.y += a.y;
    }
    float sc = 1.0f / fmaxf((float)(s1 - s0), 1.0f);
    *reinterpret_cast<float2*>(out + (size_t)row*HDIM + lane*2) = make_float2(acc.x*sc, acc.y*sc);
}

// ---------------- LDS-tiled GEMM: out = [relu](A@W + bias), A:[n,128] W:[128,128] ----------------
// 256 threads, 128x128 tile, BK=16; thread (tx,ty) computes rows {ty*4+i, 64+ty*4+i}
// x cols {tx*4+j, 64+tx*4+j}. As stored transposed [k][row], Ws [k][col], pitch PA.
__global__ __launch_bounds__(256) void k_gemm1_t(const float* __restrict__ A,
                                                 const float* __restrict__ W,
                                                 const float* __restrict__ bias,
                                                 float* __restrict__ out, int nrows, int relu) {
    __shared__ float As[16 * PA];
    __shared__ float Ws[16 * PA];
    const int t = threadIdx.x;
    const int tx = t & 15, ty = t >> 4;
    const int row0 = blockIdx.x * 128;
    const int sr = t >> 1, sk = (t & 1) * 8;   // A staging: row sr, k-offset sk
    const int wk = t >> 4, wc = t & 15;        // W staging: k-row wk, col chunks wc*4, 64+wc*4
    float acc[8][8];
    #pragma unroll
    for (int i = 0; i < 8; ++i)
        #pragma unroll
        for (int j = 0; j < 8; ++j) acc[i][j] = 0.f;

    const bool arow_ok = (row0 + sr) < nrows;
    const float* Arow = A + (size_t)(row0 + sr) * HDIM;

    for (int k0 = 0; k0 < HDIM; k0 += 16) {
        float4 av0 = make_float4(0.f,0.f,0.f,0.f), av1 = av0;
        if (arow_ok) {
            av0 = *(const float4*)(Arow + k0 + sk);
            av1 = *(const float4*)(Arow + k0 + sk + 4);
        }
        const float4 wv0 = *(const float4*)(W + (size_t)(k0 + wk)*HDIM + wc*4);
        const float4 wv1 = *(const float4*)(W + (size_t)(k0 + wk)*HDIM + 64 + wc*4);
        __syncthreads();
        As[(sk+0)*PA + sr] = av0.x; As[(sk+1)*PA + sr] = av0.y;
        As[(sk+2)*PA + sr] = av0.z; As[(sk+3)*PA + sr] = av0.w;
        As[(sk+4)*PA + sr] = av1.x; As[(sk+5)*PA + sr] = av1.y;
        As[(sk+6)*PA + sr] = av1.z; As[(sk+7)*PA + sr] = av1.w;
        *(float4*)(Ws + wk*PA + wc*4) = wv0;
        *(float4*)(Ws + wk*PA + 64 + wc*4) = wv1;
        __syncthreads();
        #pragma unroll
        for (int k = 0; k < 16; ++k) {
            const float4 a0 = *(const float4*)(As + k*PA + ty*4);
            const float4 a1 = *(const float4*)(As + k*PA + 64 + ty*4);
            const float4 w0 = *(const float4*)(Ws + k*PA + tx*4);
            const float4 w1 = *(const float4*)(Ws + k*PA + 64 + tx*4);
            const float a[8] = {a0.x,a0.y,a0.z,a0.w,a1.x,a1.y,a1.z,a1.w};
            const float w[8] = {w0.x,w0.y,w0.z,w0.w,w1.x,w1.y,w1.z,w1.w};
            #pragma unroll
            for (int i = 0; i < 8; ++i)
                #pragma unroll
                for (int j = 0; j < 8; ++j)
                    acc[i][j] += a[i]*w[j];
        }
    }
    const float4 b0 = *(const float4*)(bias + tx*4);
    const float4 b1 = *(const float4*)(bias + 64 + tx*4);
    const float bj[8] = {b0.x,b0.y,b0.z,b0.w,b1.x,b1.y,b1.z,b1.w};
    #pragma unroll
    for (int i = 0; i < 8; ++i) {
        int r = row0 + ((i < 4) ? (ty*4 + i) : (64 + ty*4 + i - 4));
        if (r >= nrows) continue;
        float o[8];
        #pragma unroll
        for (int j = 0; j < 8; ++j) {
            float v = acc[i][j] + bj[j];
            o[j] = relu ? fmaxf(v, 0.f) : v;
        }
        *(float4*)(out + (size_t)r*HDIM + tx*4)      = make_float4(o[0],o[1],o[2],o[3]);
        *(float4*)(out + (size_t)r*HDIM + 64 + tx*4) = make_float4(o[4],o[5],o[6],o[7]);
    }
}

// two-input variant: out = relu(A@WA + B@WB + bias)
__global__ __launch_bounds__(256) void k_gemm2_t(const float* __restrict__ A, const float* __restrict__ B,
                                                 const float* __restrict__ WA, const float* __restrict__ WB,
                                                 const float* __restrict__ bias,
                                                 float* __restrict__ out, int nrows) {
    __shared__ float As[16 * PA];
    __shared__ float Bs[16 * PA];
    __shared__ float WAs[16 * PA];
    __shared__ float WBs[16 * PA];
    const int t = threadIdx.x;
    const int tx = t & 15, ty = t >> 4;
    const int row0 = blockIdx.x * 128;
    const int sr = t >> 1, sk = (t & 1) * 8;
    const int wk = t >> 4, wc = t & 15;
    float acc[8][8];
    #pragma unroll
    for (int i = 0; i < 8; ++i)
        #pragma unroll
        for (int j = 0; j < 8; ++j) acc[i][j] = 0.f;

    const bool arow_ok = (row0 + sr) < nrows;
    const float* Arow = A + (size_t)(row0 + sr) * HDIM;
    const float* Brow = B + (size_t)(row0 + sr) * HDIM;

    for (int k0 = 0; k0 < HDIM; k0 += 16) {
        float4 av0 = make_float4(0.f,0.f,0.f,0.f), av1 = av0, bv0 = av0, bv1 = av0;
        if (arow_ok) {
            av0 = *(const float4*)(Arow + k0 + sk);
            av1 = *(const float4*)(Arow + k0 + sk + 4);
            bv0 = *(const float4*)(Brow + k0 + sk);
            bv1 = *(const float4*)(Brow + k0 + sk + 4);
        }
        const float4 wa0 = *(const float4*)(WA + (size_t)(k0 + wk)*HDIM + wc*4);
        const float4 wa1 = *(const float4*)(WA + (size_t)(k0 + wk)*HDIM + 64 + wc*4);
        const float4 wb0 = *(const float4*)(WB + (size_t)(k0 + wk)*HDIM + wc*4);
        const float4 wb1 = *(const float4*)(WB + (size_t)(k0 + wk)*HDIM + 64 + wc*4);
        __syncthreads();
        As[(sk+0)*PA + sr] = av0.x; As[(sk+1)*PA + sr] = av0.y;
        As[(sk+2)*PA + sr] = av0.z; As[(sk+3)*PA + sr] = av0.w;
        As[(sk+4)*PA + sr] = av1.x; As[(sk+5)*PA + sr] = av1.y;
        As[(sk+6)*PA + sr] = av1.z; As[(sk+7)*PA + sr] = av1.w;
        Bs[(sk+0)*PA + sr] = bv0.x; Bs[(sk+1)*PA + sr] = bv0.y;
        Bs[(sk+2)*PA + sr] = bv0.z; Bs[(sk+3)*PA + sr] = bv0.w;
        Bs[(sk+4)*PA + sr] = bv1.x; Bs[(sk+5)*PA + sr] = bv1.y;
        Bs[(sk+6)*PA + sr] = bv1.z; Bs[(sk+7)*PA + sr] = bv1.w;
        *(float4*)(WAs + wk*PA + wc*4) = wa0;
        *(float4*)(WAs + wk*PA + 64 + wc*4) = wa1;
        *(float4*)(WBs + wk*PA + wc*4) = wb0;
        *(float4*)(WBs + wk*PA + 64 + wc*4) = wb1;
        __syncthreads();
        #pragma unroll
        for (int k = 0; k < 16; ++k) {
            const float4 a0 = *(const float4*)(As + k*PA + ty*4);
            const float4 a1 = *(const float4*)(As + k*PA + 64 + ty*4);
            const float4 b0 = *(const float4*)(Bs + k*PA + ty*4);
            const float4 b1 = *(const float4*)(Bs + k*PA + 64 + ty*4);
            const float4 x0 = *(const float4*)(WAs + k*PA + tx*4);
            const float4 x1 = *(const float4*)(WAs + k*PA + 64 + tx*4);
            const float4 y0 = *(const float4*)(WBs + k*PA + tx*4);
            const float4 y1 = *(const float4*)(WBs + k*PA + 64 + tx*4);
            const float a[8]  = {a0.x,a0.y,a0.z,a0.w,a1.x,a1.y,a1.z,a1.w};
            const float b[8]  = {b0.x,b0.y,b0.z,b0.w,b1.x,b1.y,b1.z,b1.w};
            const float wa[8] = {x0.x,x0.y,x0.z,x0.w,x1.x,x1.y,x1.z,x1.w};
            const float wb[8] = {y0.x,y0.y,y0.z,y0.w,y1.x,y1.y,y1.z,y1.w};
            #pragma unroll
            for (int i = 0; i < 8; ++i)
                #pragma unroll
                for (int j = 0; j < 8; ++j)
                    acc[i][j] += a[i]*wa[j] + b[i]*wb[j];
        }
    }
    const float4 b0 = *(const float4*)(bias + tx*4);
    const float4 b1 = *(const float4*)(bias + 64 + tx*4);
    const float bj[8] = {b0.x,b0.y,b0.z,b0.w,b1.x,b1.y,b1.z,b1.w};
    #pragma unroll
    for (int i = 0; i < 8; ++i) {
        int r = row0 + ((i < 4) ? (ty*4 + i) : (64 + ty*4 + i - 4));
        if (r >= nrows) continue;
        float o[8];
        #pragma unroll
        for (int j = 0; j < 8; ++j) o[j] = fmaxf(acc[i][j] + bj[j], 0.f);
        *(float4*)(out + (size_t)r*HDIM + tx*4)      = make_float4(o[0],o[1],o[2],o[3]);
        *(float4*)(out + (size_t)r*HDIM + 64 + tx*4) = make_float4(o[4],o[5],o[6],o[7]);
    }
}

// transform h1 by W2 ([128,16], LDS-staged): one thread per row
__global__ __launch_bounds__(256) void k_trans16(const float* __restrict__ A,
                                                 const float* __restrict__ W,
                                                 float* __restrict__ out, int nrows) {
    __shared__ float Ws[HDIM * DOUT];
    const int t = threadIdx.x;
    *(float4*)(Ws + t*8)     = *(const float4*)(W + t*8);
    *(float4*)(Ws + t*8 + 4) = *(const float4*)(W + t*8 + 4);
    __syncthreads();
    int row = blockIdx.x * 256 + t;
    if (row >= nrows) return;
    const float* a = A + (size_t)row * HDIM;
    float acc[DOUT];
    #pragma unroll
    for (int j = 0; j < DOUT; ++j) acc[j] = 0.f;
    #pragma unroll 4
    for (int k = 0; k < HDIM; k += 4) {
        const float4 av = *(const float4*)(a + k);
        #pragma unroll
        for (int j = 0; j < DOUT; ++j)
            acc[j] += av.x*Ws[k*DOUT + j] + av.y*Ws[(k+1)*DOUT + j]
                    + av.z*Ws[(k+2)*DOUT + j] + av.w*Ws[(k+3)*DOUT + j];
    }
    #pragma unroll
    for (int j = 0; j < DOUT; j += 4)
        *(float4*)(out + (size_t)row*DOUT + j) = make_float4(acc[j],acc[j+1],acc[j+2],acc[j+3]);
}

// final: out[d] = gather(t0 via csr0)/deg0 + gather(t1 via csr1)/deg1 + bias
__global__ __launch_bounds__(256) void k_gather16_combine(const float* __restrict__ t0,
                                                          const float* __restrict__ t1,
                                                          const int* __restrict__ offs0,
                                                          const int* __restrict__ csr0,
                                                          const int* __restrict__ offs1,
                                                          const int* __restrict__ csr1,
                                                          const float* __restrict__ bias,
                                                          float* __restrict__ out, int nrows) {
    int t = threadIdx.x;
    int row = blockIdx.x * 64 + (t >> 2);
    if (row >= nrows) return;
    int c = (t & 3) * 4;
    float4 acc = make_float4(0.f, 0.f, 0.f, 0.f);
    int s0 = offs0[row], s1 = offs0[row + 1];
    for (int j = s0; j < s1; ++j) {
        int s = csr0[j];
        float4 v = *reinterpret_cast<const float4*>(t0 + (size_t)s*DOUT + c);
        acc.x += v.x; acc.y += v.y; acc.z += v.z; acc.w += v.w;
    }
    float sc = 1.0f / fmaxf((float)(s1 - s0), 1.0f);
    acc.x *= sc; acc.y *= sc; acc.z *= sc; acc.w *= sc;
    float4 acc2 = make_float4(0.f, 0.f, 0.f, 0.f);
    int u0 = offs1[row], u1 = offs1[row + 1];
    for (int j = u0; j < u1; ++j) {
        int s = csr1[j];
        float4 v = *reinterpret_cast<const float4*>(t1 + (size_t)s*DOUT + c);
        acc2.x += v.x; acc2.y += v.y; acc2.z += v.z; acc2.w += v.w;
    }
    float sc2 = 1.0f / fmaxf((float)(u1 - u0), 1.0f);
    float4 bi = *reinterpret_cast<const float4*>(bias + c);
    acc.x += acc2.x*sc2 + bi.x; acc.y += acc2.y*sc2 + bi.y;
    acc.z += acc2.z*sc2 + bi.z; acc.w += acc2.w*sc2 + bi.w;
    *reinterpret_cast<float4*>(out + (size_t)row*DOUT + c) = acc;
}

extern "C" void kernel_launch(void* const* d_in, const int* in_sizes, int n_in,
                              void* d_out, int out_size, void* d_ws, size_t ws_size,
                              hipStream_t stream) {
    const float* feat_a = (const float*)d_in[0];
    const float* feat_b = (const float*)d_in[1];
    const float* basis0 = (const float*)d_in[3];
    const float* coef0  = (const float*)d_in[4];
    const float* bias0  = (const float*)d_in[5];
    const float* basis1 = (const float*)d_in[6];
    const float* coef1  = (const float*)d_in[7];
    const float* bias1  = (const float*)d_in[8];
    const float* basis2 = (const float*)d_in[9];
    const float* coef2  = (const float*)d_in[10];
    const float* bias2  = (const float*)d_in[11];
    const int* e_src[4] = {(const int*)d_in[12], (const int*)d_in[14], (const int*)d_in[16], (const int*)d_in[18]};
    const int* e_dst[4] = {(const int*)d_in[13], (const int*)d_in[15], (const int*)d_in[17], (const int*)d_in[19]};
    const int  E[4]     = {in_sizes[12], in_sizes[14], in_sizes[16], in_sizes[18]};
    const int  Nd[4]    = {ND, ND, NA, NB};   // dst-node counts per relation

    // ---- workspace carve-up (256B-aligned chunks) ----
    char* base = (char*)d_ws;
    auto alloc = [&](size_t bytes) { char* p = base; base += (bytes + 255) & ~(size_t)255; return p; };
    float* W00 = (float*)alloc(HDIM*HDIM*4);
    float* W01 = (float*)alloc(HDIM*HDIM*4);
    float* W12 = (float*)alloc(HDIM*HDIM*4);
    float* W13 = (float*)alloc(HDIM*HDIM*4);
    float* W20 = (float*)alloc(HDIM*DOUT*4);
    float* W21 = (float*)alloc(HDIM*DOUT*4);
    int* offs[4]; int* csr[4];
    for (int r = 0; r < 4; ++r) offs[r] = (int*)alloc((Nd[r] + 1) * 4);
    for (int r = 0; r < 4; ++r) csr[r]  = (int*)alloc((size_t)E[r] * 4);
    int* bsum   = (int*)alloc(1024 * 4);
    int* ideg   = (int*)alloc(NA * 4);       // reused per relation
    int* cursor = (int*)alloc(NA * 4);       // reused per relation
    float* agg  = (float*)alloc((size_t)NA*HDIM*4);   // scratch (also t1a/t1b home)
    float* h0d  = (float*)alloc((size_t)ND*HDIM*4);
    float* h1a  = (float*)alloc((size_t)NA*HDIM*4);
    float* h1b  = (float*)alloc((size_t)NB*HDIM*4);
    float* aggA = agg;                       // [ND,128] layer-0
    float* aggB = agg + (size_t)ND*HDIM;
    float* t1a  = agg;                       // [NA,16] layer-2 (agg dead by then)
    float* t1b  = agg + (size_t)NA*DOUT;
    float* out  = (float*)d_out;

    // ---- 1. relation weights ----
    k_weights<<<(HDIM*HDIM+255)/256, 256, 0, stream>>>(basis0, coef0, W00, W01, 0, 1, HDIM*HDIM);
    k_weights<<<(HDIM*HDIM+255)/256, 256, 0, stream>>>(basis1, coef1, W12, W13, 2, 3, HDIM*HDIM);
    k_weights<<<(HDIM*DOUT+255)/256, 256, 0, stream>>>(basis2, coef2, W20, W21, 0, 1, HDIM*DOUT);

    // ---- 2. CSR per relation ----
    for (int r = 0; r < 4; ++r) {
        int N = Nd[r], e = E[r];
        int nb = (N + 255) / 256;
        hipMemsetAsync(ideg, 0, (size_t)N * 4, stream);
        k_degree_i<<<(e+255)/256, 256, 0, stream>>>(e_dst[r], e, ideg);
        k_scan1<<<nb, 256, 0, stream>>>(ideg, offs[r], bsum, N);
        k_scan2<<<1, 1024, 0, stream>>>(bsum, nb);
        k_scan3<<<nb, 256, 0, stream>>>(offs[r], bsum, N);
        k_copy_i<<<nb, 256, 0, stream>>>(offs[r], cursor, N);
        k_fill<<<(e+255)/256, 256, 0, stream>>>(e_src[r], e_dst[r], e, cursor, csr[r]);
    }

    // ---- 3. layer 0: h0d = relu(agg_a @ W00 + agg_b @ W01 + bias0) ----
    k_gather128<<<(ND+3)/4, 256, 0, stream>>>(feat_a, offs[0], csr[0], aggA, ND);
    k_gather128<<<(ND+3)/4, 256, 0, stream>>>(feat_b, offs[1], csr[1], aggB, ND);
    k_gemm2_t<<<(ND+127)/128, 256, 0, stream>>>(aggA, aggB, W00, W01, bias0, h0d, ND);

    // ---- 4. layer 1: h1a, h1b ----
    k_gather128<<<(NA+3)/4, 256, 0, stream>>>(h0d, offs[2], csr[2], h1b, NA);   // borrow h1b as scratch
    k_gemm1_t<<<(NA+127)/128, 256, 0, stream>>>(h1b, W12, bias1, h1a, NA, 1);
    k_gather128<<<(NB+3)/4, 256, 0, stream>>>(h0d, offs[3], csr[3], agg, NB);
    k_gemm1_t<<<(NB+127)/128, 256, 0, stream>>>(agg, W13, bias1, h1b, NB, 1);

    // ---- 5. layer 2 (transform-then-aggregate, dout=16) ----
    k_trans16<<<(NA+255)/256, 256, 0, stream>>>(h1a, W20, t1a, NA);
    k_trans16<<<(NB+255)/256, 256, 0, stream>>>(h1b, W21, t1b, NB);
    k_gather16_combine<<<(ND+63)/64, 256, 0, stream>>>(t1a, t1b, offs[0], csr[0], offs[1], csr[1],
                                                       bias2, out, ND);
}